// Round 1
// baseline (1178.225 us; speedup 1.0000x reference)
//
#include <hip/hip_runtime.h>
#include <math.h>

#define B     64
#define D     256
#define SIZE  4096
#define IMG   65536      // C*H*W = 1*256*256
#define NS    16         // feature slices for partial argmax
#define SLICE 256        // features per slice (SIZE/NS)

// ---------------- normalize queries ----------------
// grid: B blocks, D threads. qn[b][t] = q[b][t] / max(||q[b]||, 1e-12)
__global__ void knorm(const float* __restrict__ q, float* __restrict__ qn) {
    int b = blockIdx.x, t = threadIdx.x;
    float x = q[b * D + t];
    __shared__ float red[D];
    red[t] = x * x;
    __syncthreads();
    for (int s = D / 2; s > 0; s >>= 1) {
        if (t < s) red[t] += red[t + s];
        __syncthreads();
    }
    float denom = fmaxf(sqrtf(red[0]), 1e-12f);
    qn[b * D + t] = x / denom;
}

// ---------------- partial sim + argmax ----------------
// grid: (NS, B), block 256 (4 waves). Each wave handles 64 consecutive
// features: lane l holds q[b][4l..4l+3]; per feature, coalesced float4 read of
// the feature row, dot4, 64-lane butterfly reduce. Strict '>' over increasing
// f keeps the FIRST max (jnp.argmax semantics).
__global__ void kpartial(const float* __restrict__ qn,
                         const float* __restrict__ feat,
                         float* __restrict__ pval, int* __restrict__ pidx) {
    const int b    = blockIdx.y;
    const int sl   = blockIdx.x;
    const int lane = threadIdx.x & 63;
    const int wave = threadIdx.x >> 6;

    const float4 qv = *(const float4*)(qn + b * D + lane * 4);

    float best = -INFINITY;
    int   bidx = 0;
    const int f0 = sl * SLICE + wave * 64;
    for (int ff = 0; ff < 64; ++ff) {
        int f = f0 + ff;
        float4 fv = *(const float4*)(feat + (size_t)f * D + lane * 4);
        float s = qv.x * fv.x + qv.y * fv.y + qv.z * fv.z + qv.w * fv.w;
        #pragma unroll
        for (int off = 32; off >= 1; off >>= 1) s += __shfl_xor(s, off, 64);
        if (s > best) { best = s; bidx = f; }   // first occurrence wins
    }

    __shared__ float wv[4];
    __shared__ int   wi[4];
    if (lane == 0) { wv[wave] = best; wi[wave] = bidx; }
    __syncthreads();
    if (threadIdx.x == 0) {
        // waves cover increasing f ranges -> strict '>' keeps first max
        float v = wv[0]; int i = wi[0];
        for (int w = 1; w < 4; ++w) {
            if (wv[w] > v) { v = wv[w]; i = wi[w]; }
        }
        pval[b * NS + sl] = v;
        pidx[b * NS + sl] = i;
    }
}

// ---------------- final reduce over slices ----------------
// grid: B blocks, 64 threads (1 wave). Tie-break: equal value -> smaller index.
__global__ void kfinal(const float* __restrict__ pval,
                       const int* __restrict__ pidx,
                       float* __restrict__ scores, int* __restrict__ fidx) {
    int b = blockIdx.x, t = threadIdx.x;
    float v = -INFINITY;
    int   i = 0x7fffffff;
    if (t < NS) { v = pval[b * NS + t]; i = pidx[b * NS + t]; }
    #pragma unroll
    for (int off = 32; off >= 1; off >>= 1) {
        float ov = __shfl_xor(v, off, 64);
        int   oi = __shfl_xor(i, off, 64);
        if (ov > v || (ov == v && oi < i)) { v = ov; i = oi; }
    }
    if (t == 0) { scores[b] = v; fidx[b] = i; }
}

// ---------------- gather images ----------------
// grid: (IMG/1024, B), block 256. Each thread copies one float4 (coalesced,
// 16B/lane). Row of 65536 floats = 64 blocks x 256 threads x float4.
__global__ void kgather(const float* __restrict__ imgs,
                        const int* __restrict__ fidx,
                        float* __restrict__ out) {
    int b   = blockIdx.y;
    int idx = fidx[b];
    size_t off = ((size_t)blockIdx.x * 256 + threadIdx.x) * 4;
    const float4 v = *(const float4*)(imgs + (size_t)idx * IMG + off);
    *(float4*)(out + (size_t)b * IMG + off) = v;
}

extern "C" void kernel_launch(void* const* d_in, const int* in_sizes, int n_in,
                              void* d_out, int out_size, void* d_ws, size_t ws_size,
                              hipStream_t stream) {
    const float* q    = (const float*)d_in[0];  // (64, 256)
    const float* feat = (const float*)d_in[1];  // (4096, 256), pre-normalized
    const float* imgs = (const float*)d_in[2];  // (4096, 65536)
    float* out = (float*)d_out;                 // [imgs (64*65536) | scores (64)]

    // workspace layout (floats/ints), ~80 KB total
    float* qn   = (float*)d_ws;                 // B*D
    float* pval = qn + B * D;                   // B*NS
    int*   pidx = (int*)(pval + B * NS);        // B*NS
    int*   fidx = pidx + B * NS;                // B

    knorm<<<B, D, 0, stream>>>(q, qn);
    kpartial<<<dim3(NS, B), 256, 0, stream>>>(qn, feat, pval, pidx);
    kfinal<<<B, 64, 0, stream>>>(pval, pidx, out + (size_t)B * IMG, fidx);
    kgather<<<dim3(IMG / 1024, B), 256, 0, stream>>>(imgs, fidx, out);
}